// Round 5
// baseline (422.370 us; speedup 1.0000x reference)
//
#include <hip/hip_runtime.h>

// VectorQuantizer on MI355X (gfx950), v5r: phase-split kernels (resubmit of
// v5 after infra failure; only change: explicit 16B LDS alignment).
// vq_prep:    codebook -> bf16 pre-swizzled tiles + norms + fp32 transpose e_T.
// vq_argmin:  256-thr blocks, wave = one 64-row line; per-wave private LDS
//             quarter staging of x (coalesced 256B loads, no barriers);
//             32-code dbuf tiles via global_load_lds, counted vmcnt(4);
//             writes fi + loss only.
// vq_scatter: pure-BW output: LDS-resident e_T tile + fi line, gather, write
//             contiguous 8d x 4096hw slab per block.

#define DIN 256

typedef __attribute__((ext_vector_type(8))) short short8;
typedef __attribute__((ext_vector_type(4))) float float4v;
typedef __attribute__((ext_vector_type(4))) unsigned short ushort4v;
typedef __attribute__((ext_vector_type(4))) int int4v;

static __device__ __forceinline__ unsigned short f2bf(float f) {
  unsigned int u = __float_as_uint(f);
  unsigned int r = (u + 0x7fffu + ((u >> 16) & 1u)) >> 16;  // RNE
  return (unsigned short)r;
}

__global__ void vq_prep(const float* __restrict__ e,
                        unsigned short* __restrict__ e_pre,
                        float* __restrict__ norms,
                        float* __restrict__ eT) {
  int wave = threadIdx.x >> 6, lane = threadIdx.x & 63;
  int k = blockIdx.x * 4 + wave;
  const float4v* src = (const float4v*)(e + k * DIN);
  float4v v = src[lane];
  float ss = v[0]*v[0] + v[1]*v[1] + v[2]*v[2] + v[3]*v[3];
  ushort4v pk;
  pk[0] = f2bf(v[0]); pk[1] = f2bf(v[1]); pk[2] = f2bf(v[2]); pk[3] = f2bf(v[3]);
  int t = k >> 5, kL = k & 31;
  int cc = lane >> 1, half = lane & 1;       // 16B chunk, 8B half
  int s = cc ^ (kL & 7);
  *(ushort4v*)(e_pre + t * 8192 + kL * 256 + s * 8 + half * 4) = pk;
  #pragma unroll
  for (int ii = 0; ii < 4; ++ii)             // fp32 transpose for scatter
    eT[(lane * 4 + ii) * 1024 + k] = v[ii];
  #pragma unroll
  for (int m = 1; m < 64; m <<= 1) ss += __shfl_xor(ss, m, 64);
  if (lane == 0) norms[k] = ss;
}

#define BARRIER_RAW() do { asm volatile("" ::: "memory"); \
  __builtin_amdgcn_s_barrier(); asm volatile("" ::: "memory"); } while (0)

__global__ void __launch_bounds__(256, 2)
vq_argmin(const float* __restrict__ xin,
          const unsigned short* __restrict__ e_pre,
          const float* __restrict__ norms,
          int* __restrict__ fig, float* __restrict__ loss_acc) {
  // [0,32768) es dbuf 2x16KB | [32768,65536) xs: 4 waves x 8KB private
  // [65536,69632) nrm[1024]  | [69632,+16) prt[4]
  __shared__ __align__(16) char smem[69648];
  float* nrm = (float*)(smem + 65536);
  float* prt = (float*)(smem + 69632);

  const int tid  = threadIdx.x;
  const int wave = tid >> 6, lane = tid & 63;
  const int m16  = lane & 15, quad = lane >> 4;
  const int line = blockIdx.x * 4 + wave;    // wave owns one (b,h) line
  const float* xl = xin + (line >> 6) * 1048576 + (line & 63) * 64;

  // stage tile t (16 KB) into buffer buf: 4 DMA issues/thread, linear dest
  auto stage = [&](int t, int buf) {
    const char* src = (const char*)e_pre + t * 16384;
    char* dst = smem + buf * 16384;
    #pragma unroll
    for (int j = 0; j < 4; ++j) {
      int off = j * 4096 + tid * 16;
      __builtin_amdgcn_global_load_lds(
          (const __attribute__((address_space(1))) unsigned int*)(src + off),
          (__attribute__((address_space(3))) unsigned int*)(dst + off),
          16, 0, 0);
    }
  };
  stage(0, 0);                               // overlaps with prologue

  *(float4v*)(nrm + tid * 4) = *(const float4v*)(norms + tid * 4);

  // ---- prologue: own-line staging through private 8KB slot, d-quarters ----
  // thread handles row w=lane for all d: loads are 256B coalesced per instr;
  // ssq = full fp32 row norm per thread. No barriers (private slot,
  // same-wave DS ops are processed in order).
  unsigned short* xsw = (unsigned short*)(smem + 32768 + wave * 8192);
  short8 areg[32];                           // 4 rowfrags x 8 ksteps
  float ssq = 0.0f;
  #pragma unroll
  for (int q = 0; q < 4; ++q) {              // d-quarter: 64 d values
    #pragma unroll
    for (int c = 0; c < 8; ++c) {            // 8 chunks of 8 d
      short8 pk;
      #pragma unroll
      for (int ii = 0; ii < 8; ++ii) {
        float xv = xl[(q * 64 + c * 8 + ii) * 4096 + lane];
        ssq += xv * xv;
        pk[ii] = (short)f2bf(xv);
      }
      *(short8*)(xsw + lane * 64 + ((c ^ (lane & 7)) * 8)) = pk;
    }
    #pragma unroll
    for (int i = 0; i < 4; ++i)              // frag reads for kk = 2q, 2q+1
      #pragma unroll
      for (int kl = 0; kl < 2; ++kl) {
        int r = i * 16 + m16;
        int cl = kl * 4 + quad;
        areg[i * 8 + q * 2 + kl] =
            *(short8*)(xsw + r * 64 + ((cl ^ (r & 7)) * 8));
      }
  }
  asm volatile("s_waitcnt lgkmcnt(0)" ::: "memory");  // nrm/xs flushed

  float bestv[4][4];
  int   besti[4][4];
  #pragma unroll
  for (int i = 0; i < 4; ++i)
    #pragma unroll
    for (int r = 0; r < 4; ++r) { bestv[i][r] = INFINITY; besti[i][r] = 0; }

  // ---- GEMM: 32 code tiles, double-buffered, counted vmcnt ----
  for (int t = 0; t < 32; ++t) {
    if (t < 31) {
      stage(t + 1, (t + 1) & 1);
      asm volatile("s_waitcnt vmcnt(4)" ::: "memory");   // tile t landed
    } else {
      asm volatile("s_waitcnt vmcnt(0)" ::: "memory");
    }
    BARRIER_RAW();
    const unsigned short* eb = (const unsigned short*)(smem + (t & 1) * 16384);
    #pragma unroll
    for (int j = 0; j < 2; ++j) {
      int cL = j * 16 + m16;
      float4v a0 = (float4v)(0.0f), a1 = (float4v)(0.0f);
      float4v a2 = (float4v)(0.0f), a3 = (float4v)(0.0f);
      #pragma unroll
      for (int kk = 0; kk < 8; ++kk) {
        short8 bfr = *(const short8*)(eb + cL * 256 + 8 * ((kk * 4 + quad) ^ (cL & 7)));
        a0 = __builtin_amdgcn_mfma_f32_16x16x32_bf16(areg[kk],      bfr, a0, 0, 0, 0);
        a1 = __builtin_amdgcn_mfma_f32_16x16x32_bf16(areg[8 + kk],  bfr, a1, 0, 0, 0);
        a2 = __builtin_amdgcn_mfma_f32_16x16x32_bf16(areg[16 + kk], bfr, a2, 0, 0, 0);
        a3 = __builtin_amdgcn_mfma_f32_16x16x32_bf16(areg[24 + kk], bfr, a3, 0, 0, 0);
      }
      int col = t * 32 + cL;
      float nj = nrm[col];
      #pragma unroll
      for (int r = 0; r < 4; ++r) {
        float s0 = nj - 2.0f * a0[r];
        if (s0 < bestv[0][r]) { bestv[0][r] = s0; besti[0][r] = col; }
        float s1 = nj - 2.0f * a1[r];
        if (s1 < bestv[1][r]) { bestv[1][r] = s1; besti[1][r] = col; }
        float s2 = nj - 2.0f * a2[r];
        if (s2 < bestv[2][r]) { bestv[2][r] = s2; besti[2][r] = col; }
        float s3 = nj - 2.0f * a3[r];
        if (s3 < bestv[3][r]) { bestv[3][r] = s3; besti[3][r] = col; }
      }
    }
    BARRIER_RAW();
  }

  // ---- cross-lane argmin over the 16 col-lanes (tie -> smaller idx) ----
  #pragma unroll
  for (int msk = 1; msk <= 8; msk <<= 1) {
    #pragma unroll
    for (int i = 0; i < 4; ++i)
      #pragma unroll
      for (int r = 0; r < 4; ++r) {
        float ov = __shfl_xor(bestv[i][r], msk, 64);
        int   oi = __shfl_xor(besti[i][r], msk, 64);
        if (ov < bestv[i][r] || (ov == bestv[i][r] && oi < besti[i][r])) {
          bestv[i][r] = ov; besti[i][r] = oi;
        }
      }
  }

  // ---- fi + loss: loss = sum(||x||^2) + sum(bestv) over rows ----
  float lsum = ssq;                          // every thread owns one row norm
  if (m16 == 0) {
    #pragma unroll
    for (int i = 0; i < 4; ++i)
      #pragma unroll
      for (int r = 0; r < 4; ++r) {
        int row = i * 16 + quad * 4 + r;
        fig[line * 64 + row] = besti[i][r];
        lsum += bestv[i][r];
      }
  }
  #pragma unroll
  for (int msk = 1; msk < 64; msk <<= 1) lsum += __shfl_xor(lsum, msk, 64);
  if (lane == 0) prt[wave] = lsum;
  __syncthreads();
  if (tid == 0)
    atomicAdd(loss_acc, prt[0] + prt[1] + prt[2] + prt[3]);
}

__global__ void __launch_bounds__(256, 3)
vq_scatter(const float* __restrict__ eT, const int* __restrict__ fig,
           float* __restrict__ out) {
  // [0,32768) eT tile [8][1024] f32 | [32768,49152) fi line [4096] i32
  __shared__ __align__(16) char smem[49152];
  float* eTl = (float*)smem;
  int*   fil = (int*)(smem + 32768);
  const int tid = threadIdx.x;
  const int b = blockIdx.x >> 5, dc = blockIdx.x & 31;  // 8-d chunk

  const char* s0 = (const char*)eT + dc * 32768;
  #pragma unroll
  for (int j = 0; j < 8; ++j) {
    int off = j * 4096 + tid * 16;
    __builtin_amdgcn_global_load_lds(
        (const __attribute__((address_space(1))) unsigned int*)(s0 + off),
        (__attribute__((address_space(3))) unsigned int*)(smem + off),
        16, 0, 0);
  }
  const char* s1 = (const char*)(fig + b * 4096);
  #pragma unroll
  for (int j = 0; j < 4; ++j) {
    int off = j * 4096 + tid * 16;
    __builtin_amdgcn_global_load_lds(
        (const __attribute__((address_space(1))) unsigned int*)(s1 + off),
        (__attribute__((address_space(3))) unsigned int*)(smem + 32768 + off),
        16, 0, 0);
  }
  asm volatile("s_waitcnt vmcnt(0)" ::: "memory");
  __syncthreads();

  float* ob = out + 1 + b * 1048576 + dc * 8 * 4096;
  for (int ro = 0; ro < 4; ++ro) {
    int p = ro * 1024 + tid * 4;
    int4v idx = *(const int4v*)(fil + p);
    #pragma unroll
    for (int d = 0; d < 8; ++d) {
      float4v v;
      v[0] = eTl[d * 1024 + idx[0]];
      v[1] = eTl[d * 1024 + idx[1]];
      v[2] = eTl[d * 1024 + idx[2]];
      v[3] = eTl[d * 1024 + idx[3]];
      *(float4v*)(ob + d * 4096 + p) = v;    // 1KB span per wave-instr
    }
  }
}

__global__ void vq_fin(const float* __restrict__ loss_acc,
                       const float* __restrict__ beta,
                       float* __restrict__ out) {
  out[0] = (1.0f + beta[0]) * loss_acc[0] / 33554432.0f;
}

extern "C" void kernel_launch(void* const* d_in, const int* in_sizes, int n_in,
                              void* d_out, int out_size, void* d_ws, size_t ws_size,
                              hipStream_t stream) {
  const float* xin  = (const float*)d_in[0];
  const float* emb  = (const float*)d_in[1];
  const float* beta = (const float*)d_in[2];
  float* out = (float*)d_out;
  float* loss_acc = (float*)d_ws;                                 // 4 B
  float* norms = (float*)((char*)d_ws + 4096);                    // 4 KB
  unsigned short* e_pre = (unsigned short*)((char*)d_ws + 8192);  // 512 KB
  float* eT = (float*)((char*)d_ws + 532480);                     // 1 MB
  int* fig = (int*)((char*)d_ws + 1581056);                       // 512 KB

  hipMemsetAsync(d_ws, 0, 4, stream);
  vq_prep<<<256, 256, 0, stream>>>(emb, e_pre, norms, eT);
  vq_argmin<<<512, 256, 0, stream>>>(xin, e_pre, norms, fig, loss_acc);
  vq_scatter<<<1024, 256, 0, stream>>>(eT, fig, out);
  vq_fin<<<1, 1, 0, stream>>>(loss_acc, beta, out);
}

// Round 7
// 376.865 us; speedup vs baseline: 1.1207x; 1.1207x over previous
//
#include <hip/hip_runtime.h>

// VectorQuantizer on MI355X (gfx950), v6r: phase-split, spill-free argmin
// (identical resubmit of v6 after GPU-acquisition infra failure).
// vq_argmin: 256-thr blocks, 32 rows/wave (areg[16] = 32 VGPR -> no scratch),
//            2 lines/block, per-wave private x staging (coalesced, barrier-
//            free); 32-code dbuf tiles via global_load_lds, counted vmcnt(4).
// vq_scatter: pure-BW output via LDS-resident e_T tile + fi line.

#define DIN 256

typedef __attribute__((ext_vector_type(8))) short short8;
typedef __attribute__((ext_vector_type(4))) float float4v;
typedef __attribute__((ext_vector_type(4))) unsigned short ushort4v;
typedef __attribute__((ext_vector_type(4))) int int4v;

static __device__ __forceinline__ unsigned short f2bf(float f) {
  unsigned int u = __float_as_uint(f);
  unsigned int r = (u + 0x7fffu + ((u >> 16) & 1u)) >> 16;  // RNE
  return (unsigned short)r;
}

__global__ void vq_prep(const float* __restrict__ e,
                        unsigned short* __restrict__ e_pre,
                        float* __restrict__ norms,
                        float* __restrict__ eT) {
  int wave = threadIdx.x >> 6, lane = threadIdx.x & 63;
  int k = blockIdx.x * 4 + wave;
  const float4v* src = (const float4v*)(e + k * DIN);
  float4v v = src[lane];
  float ss = v[0]*v[0] + v[1]*v[1] + v[2]*v[2] + v[3]*v[3];
  ushort4v pk;
  pk[0] = f2bf(v[0]); pk[1] = f2bf(v[1]); pk[2] = f2bf(v[2]); pk[3] = f2bf(v[3]);
  int t = k >> 5, kL = k & 31;
  int cc = lane >> 1, half = lane & 1;       // 16B chunk, 8B half
  int s = cc ^ (kL & 7);
  *(ushort4v*)(e_pre + t * 8192 + kL * 256 + s * 8 + half * 4) = pk;
  #pragma unroll
  for (int ii = 0; ii < 4; ++ii)             // fp32 transpose for scatter
    eT[(lane * 4 + ii) * 1024 + k] = v[ii];
  #pragma unroll
  for (int m = 1; m < 64; m <<= 1) ss += __shfl_xor(ss, m, 64);
  if (lane == 0) norms[k] = ss;
}

#define BARRIER_RAW() do { asm volatile("" ::: "memory"); \
  __builtin_amdgcn_s_barrier(); asm volatile("" ::: "memory"); } while (0)

__global__ void __launch_bounds__(256, 3)
vq_argmin(const float* __restrict__ xin,
          const unsigned short* __restrict__ e_pre,
          const float* __restrict__ norms,
          int* __restrict__ fig, float* __restrict__ loss_acc) {
  // [0,32768) es dbuf 2x16KB | [32768,49152) xs: 4 waves x 4KB private
  // [49152,53248) nrm[1024]  | [53248,+16) prt[4]
  __shared__ __align__(16) char smem[53264];
  float* nrm = (float*)(smem + 49152);
  float* prt = (float*)(smem + 53248);

  const int tid  = threadIdx.x;
  const int wave = tid >> 6, lane = tid & 63;
  const int m16  = lane & 15, quad = lane >> 4;
  const int line = blockIdx.x * 2 + (wave >> 1);  // 2 lines/block
  const int r32  = (wave & 1) * 32;               // wave's 32-row half
  const float* xl = xin + (line >> 6) * 1048576 + (line & 63) * 64;

  // stage tile t (16 KB) into buffer buf: 4 DMA issues/thread, linear dest
  auto stage = [&](int t, int buf) {
    const char* src = (const char*)e_pre + t * 16384;
    char* dst = smem + buf * 16384;
    #pragma unroll
    for (int j = 0; j < 4; ++j) {
      int off = j * 4096 + tid * 16;
      __builtin_amdgcn_global_load_lds(
          (const __attribute__((address_space(1))) unsigned int*)(src + off),
          (__attribute__((address_space(3))) unsigned int*)(dst + off),
          16, 0, 0);
    }
  };
  stage(0, 0);                               // overlaps with prologue

  *(float4v*)(nrm + tid * 4) = *(const float4v*)(norms + tid * 4);

  // ---- prologue: private per-wave staging, quarter at a time ----
  // thread owns row rl (of its wave's 32) and d-half dh of each quarter:
  // loads are 2x128B coalesced per wave-instr; ssq sums this thread's 128
  // x^2 values (sum over all threads = sum over all elements).
  unsigned short* xsw = (unsigned short*)(smem + 32768 + wave * 4096);
  const int rl = lane & 31;                  // local row 0..31
  const int dh = lane >> 5;                  // d-half of quarter
  short8 areg[16];                           // 2 rowfrags x 8 ksteps = 32 VGPR
  float ssq = 0.0f;
  #pragma unroll
  for (int q = 0; q < 4; ++q) {              // d-quarter: 64 d values
    #pragma unroll
    for (int c = 0; c < 4; ++c) {            // 4 chunks of 8 d per half
      short8 pk;
      #pragma unroll
      for (int ii = 0; ii < 8; ++ii) {
        float xv = xl[(q * 64 + dh * 32 + c * 8 + ii) * 4096 + r32 + rl];
        ssq += xv * xv;
        pk[ii] = (short)f2bf(xv);
      }
      int cc = dh * 4 + c;                   // chunk 0..7 within quarter
      *(short8*)(xsw + rl * 64 + 8 * (cc ^ (rl & 7))) = pk;
    }
    asm volatile("s_waitcnt lgkmcnt(0)" ::: "memory");  // writes visible
    #pragma unroll
    for (int i = 0; i < 2; ++i)              // frag reads for kk = 2q, 2q+1
      #pragma unroll
      for (int kl = 0; kl < 2; ++kl) {
        int r = i * 16 + m16;
        areg[i * 8 + q * 2 + kl] =
            *(short8*)(xsw + r * 64 + 8 * ((kl * 4 + quad) ^ (r & 7)));
      }
    asm volatile("" ::: "memory");           // keep reads before next writes
  }
  asm volatile("s_waitcnt lgkmcnt(0)" ::: "memory");  // nrm/frag reads done

  float bestv[2][4];
  int   besti[2][4];
  #pragma unroll
  for (int i = 0; i < 2; ++i)
    #pragma unroll
    for (int r = 0; r < 4; ++r) { bestv[i][r] = INFINITY; besti[i][r] = 0; }

  // ---- GEMM: 32 code tiles, double-buffered, counted vmcnt ----
  for (int t = 0; t < 32; ++t) {
    if (t < 31) {
      stage(t + 1, (t + 1) & 1);
      asm volatile("s_waitcnt vmcnt(4)" ::: "memory");   // tile t landed
    } else {
      asm volatile("s_waitcnt vmcnt(0)" ::: "memory");
    }
    BARRIER_RAW();
    const unsigned short* eb = (const unsigned short*)(smem + (t & 1) * 16384);
    #pragma unroll
    for (int j = 0; j < 2; ++j) {
      int cL = j * 16 + m16;
      float4v a0 = (float4v)(0.0f), a1 = (float4v)(0.0f);
      #pragma unroll
      for (int kk = 0; kk < 8; ++kk) {
        short8 bfr = *(const short8*)(eb + cL * 256 + 8 * ((kk * 4 + quad) ^ (cL & 7)));
        a0 = __builtin_amdgcn_mfma_f32_16x16x32_bf16(areg[kk],     bfr, a0, 0, 0, 0);
        a1 = __builtin_amdgcn_mfma_f32_16x16x32_bf16(areg[8 + kk], bfr, a1, 0, 0, 0);
      }
      int col = t * 32 + cL;
      float nj = nrm[col];
      #pragma unroll
      for (int r = 0; r < 4; ++r) {
        float s0 = nj - 2.0f * a0[r];
        if (s0 < bestv[0][r]) { bestv[0][r] = s0; besti[0][r] = col; }
        float s1 = nj - 2.0f * a1[r];
        if (s1 < bestv[1][r]) { bestv[1][r] = s1; besti[1][r] = col; }
      }
    }
    BARRIER_RAW();
  }

  // ---- cross-lane argmin over the 16 col-lanes (tie -> smaller idx) ----
  #pragma unroll
  for (int msk = 1; msk <= 8; msk <<= 1) {
    #pragma unroll
    for (int i = 0; i < 2; ++i)
      #pragma unroll
      for (int r = 0; r < 4; ++r) {
        float ov = __shfl_xor(bestv[i][r], msk, 64);
        int   oi = __shfl_xor(besti[i][r], msk, 64);
        if (ov < bestv[i][r] || (ov == bestv[i][r] && oi < besti[i][r])) {
          bestv[i][r] = ov; besti[i][r] = oi;
        }
      }
  }

  // ---- fi + loss: loss = sum(||x||^2) + sum(bestv) over rows ----
  float lsum = ssq;                          // thread's partial sum of x^2
  if (m16 == 0) {
    #pragma unroll
    for (int i = 0; i < 2; ++i)
      #pragma unroll
      for (int r = 0; r < 4; ++r) {
        int row = r32 + i * 16 + quad * 4 + r;
        fig[line * 64 + row] = besti[i][r];
        lsum += bestv[i][r];
      }
  }
  #pragma unroll
  for (int msk = 1; msk < 64; msk <<= 1) lsum += __shfl_xor(lsum, msk, 64);
  if (lane == 0) prt[wave] = lsum;
  __syncthreads();
  if (tid == 0)
    atomicAdd(loss_acc, prt[0] + prt[1] + prt[2] + prt[3]);
}

__global__ void __launch_bounds__(256, 3)
vq_scatter(const float* __restrict__ eT, const int* __restrict__ fig,
           float* __restrict__ out) {
  // [0,32768) eT tile [8][1024] f32 | [32768,49152) fi line [4096] i32
  __shared__ __align__(16) char smem[49152];
  float* eTl = (float*)smem;
  int*   fil = (int*)(smem + 32768);
  const int tid = threadIdx.x;
  const int b = blockIdx.x >> 5, dc = blockIdx.x & 31;  // 8-d chunk

  const char* s0 = (const char*)eT + dc * 32768;
  #pragma unroll
  for (int j = 0; j < 8; ++j) {
    int off = j * 4096 + tid * 16;
    __builtin_amdgcn_global_load_lds(
        (const __attribute__((address_space(1))) unsigned int*)(s0 + off),
        (__attribute__((address_space(3))) unsigned int*)(smem + off),
        16, 0, 0);
  }
  const char* s1 = (const char*)(fig + b * 4096);
  #pragma unroll
  for (int j = 0; j < 4; ++j) {
    int off = j * 4096 + tid * 16;
    __builtin_amdgcn_global_load_lds(
        (const __attribute__((address_space(1))) unsigned int*)(s1 + off),
        (__attribute__((address_space(3))) unsigned int*)(smem + 32768 + off),
        16, 0, 0);
  }
  asm volatile("s_waitcnt vmcnt(0)" ::: "memory");
  __syncthreads();

  float* ob = out + 1 + b * 1048576 + dc * 8 * 4096;
  for (int ro = 0; ro < 4; ++ro) {
    int p = ro * 1024 + tid * 4;
    int4v idx = *(const int4v*)(fil + p);
    #pragma unroll
    for (int d = 0; d < 8; ++d) {
      float4v v;
      v[0] = eTl[d * 1024 + idx[0]];
      v[1] = eTl[d * 1024 + idx[1]];
      v[2] = eTl[d * 1024 + idx[2]];
      v[3] = eTl[d * 1024 + idx[3]];
      *(float4v*)(ob + d * 4096 + p) = v;    // part of a 16KB span per d
    }
  }
}

__global__ void vq_fin(const float* __restrict__ loss_acc,
                       const float* __restrict__ beta,
                       float* __restrict__ out) {
  out[0] = (1.0f + beta[0]) * loss_acc[0] / 33554432.0f;
}

extern "C" void kernel_launch(void* const* d_in, const int* in_sizes, int n_in,
                              void* d_out, int out_size, void* d_ws, size_t ws_size,
                              hipStream_t stream) {
  const float* xin  = (const float*)d_in[0];
  const float* emb  = (const float*)d_in[1];
  const float* beta = (const float*)d_in[2];
  float* out = (float*)d_out;
  float* loss_acc = (float*)d_ws;                                 // 4 B
  float* norms = (float*)((char*)d_ws + 4096);                    // 4 KB
  unsigned short* e_pre = (unsigned short*)((char*)d_ws + 8192);  // 512 KB
  float* eT = (float*)((char*)d_ws + 532480);                     // 1 MB
  int* fig = (int*)((char*)d_ws + 1581056);                       // 512 KB

  hipMemsetAsync(d_ws, 0, 4, stream);
  vq_prep<<<256, 256, 0, stream>>>(emb, e_pre, norms, eT);
  vq_argmin<<<1024, 256, 0, stream>>>(xin, e_pre, norms, fig, loss_acc);
  vq_scatter<<<1024, 256, 0, stream>>>(eT, fig, out);
  vq_fin<<<1, 1, 0, stream>>>(loss_acc, beta, out);
}